// Round 12
// baseline (128.301 us; speedup 1.0000x reference)
//
#include <hip/hip_runtime.h>
#include <math.h>

#define N_  4096
#define D_  128
#define B_  2
#define CL_ 64
#define CH_ 192

typedef __attribute__((ext_vector_type(8))) short short8;
typedef __attribute__((ext_vector_type(4))) float f32x4;
typedef __attribute__((ext_vector_type(16))) float f32x16;

#if __has_builtin(__builtin_amdgcn_exp2f)
#define EXP2(x) __builtin_amdgcn_exp2f(x)
#else
#define EXP2(x) exp2f(x)
#endif

__device__ __forceinline__ short f2bf(float x) {
  union { float f; unsigned u; } v; v.f = x;
  unsigned r = v.u + 0x7FFFu + ((v.u >> 16) & 1u);
  return (short)(r >> 16);
}

typedef __attribute__((address_space(1))) const void gv_t;
typedef __attribute__((address_space(3))) void sv_t;
__device__ __forceinline__ void gl_lds16(const void* g, void* l) {
  __builtin_amdgcn_global_load_lds((gv_t*)g, (sv_t*)l, 16, 0, 0);
}

#define CVTPK(d, lo, hi) asm("v_cvt_pk_bf16_f32 %0, %1, %2" : "=v"(d) : "v"(lo), "v"(hi))
#define PLSWAP(a, b) asm("v_permlane32_swap_b32 %0, %1" : "+v"(a), "+v"(b))

// ---------------------------------------------------------------------------
// XT (fused streams): f32 [C][4096] -> bf16 [n][C], granule pre-swizzled
// ^(n&7) within each 8-granule window. blockIdx.z: 0=hf(C=192), 1=ll(C=64).
// ---------------------------------------------------------------------------
__global__ __launch_bounds__(256)
void xt_kernel(const float* __restrict__ hf, const float* __restrict__ ll,
               short* __restrict__ hfT, short* __restrict__ llT) {
  __shared__ float Ls[CH_][65];
  const int tid = threadIdx.x;
  const int n0 = blockIdx.x * 64;
  const int b = blockIdx.y;
  const int s = blockIdx.z;
  const int C = s ? CL_ : CH_;
  const float* src = (s ? ll : hf) + (size_t)b * C * N_;
  short* dst = (s ? llT : hfT) + (size_t)b * N_ * C;
  for (int flat = tid; flat < C * 64; flat += 256) {
    int c = flat >> 6, nn = flat & 63;
    Ls[c][nn] = src[(size_t)c * N_ + n0 + nn];
  }
  __syncthreads();
  const int ng = C >> 3;
  for (int u = tid; u < 64 * ng; u += 256) {
    int nn = u / ng, g = u - nn * ng;
    short8 v;
    #pragma unroll
    for (int j = 0; j < 8; ++j) v[j] = f2bf(Ls[g*8 + j][nn]);
    int pos = (g & ~7) | ((g ^ (nn & 7)) & 7);
    *(short8*)(dst + (size_t)(n0 + nn) * C + pos * 8) = v;
  }
}

// ---------------------------------------------------------------------------
// Vt: Vb bf16 [d][n] -> image-transposed Vt [d][n'] (n' = w*64+h), same swizzle.
// ---------------------------------------------------------------------------
__global__ __launch_bounds__(256)
void vt_kernel(const short* __restrict__ Vhb, const short* __restrict__ Vlb,
               short* __restrict__ Vht, short* __restrict__ Vlt) {
  __shared__ short rowbuf[4 * 4096];
  const int tid = threadIdx.x;
  const int lane = tid & 63, w = tid >> 6;
  const short* src = blockIdx.y ? Vlb : Vhb;
  short* dst = blockIdx.y ? Vlt : Vht;
  const int r0 = blockIdx.x * 4;
  #pragma unroll
  for (int i = 0; i < 8; ++i) {
    int idx = i * 256 + w * 64 + lane;
    int row = idx >> 9, g = idx & 511;
    gl_lds16(src + (size_t)(r0 + row) * N_ + g * 8,
             (char*)rowbuf + i * 4096 + w * 1024 + lane * 16);
  }
  __syncthreads();
  const int rw = r0 + w, d7 = rw & 7;
  const short* rb = rowbuf + w * 4096;
  const int w0 = (lane & 7) * 8, h0 = (lane >> 3) * 8;
  short8 rr[8];
  #pragma unroll
  for (int j = 0; j < 8; ++j)
    rr[j] = *(const short8*)(rb + (h0 + j) * 64 + (((w0 >> 3) ^ d7) * 8));
  #pragma unroll
  for (int i = 0; i < 8; ++i) {
    short8 o;
    #pragma unroll
    for (int j = 0; j < 8; ++j) o[j] = rr[j][i];
    *(short8*)(dst + (size_t)rw * N_ + (w0 + i) * 64 + (((h0 >> 3) ^ d7) * 8)) = o;
  }
}

// ---------------------------------------------------------------------------
// Fused QKV MFMA GEMM, both streams in one launch (unchanged).
// ---------------------------------------------------------------------------
struct QkvP {
  const float *W0h, *W1h, *W2h, *W0l, *W1l, *W2l;
  const short *BsH, *BsL;
  short *QbH, *KbH, *VbH, *QtH, *KtH;
  short *QbL, *KbL, *VbL, *QtL, *KtL;
  float qscale;
};

__global__ __launch_bounds__(256, 4)
void qkv_kernel(QkvP g) {
  __shared__ __align__(16) char AB[16384];
  __shared__ float Epi[64][67];
  const int tid = threadIdx.x;
  const int lane = tid & 63, w = tid >> 6, m = lane & 15, hi = lane >> 4;
  const int n0 = blockIdx.x * 64;
  const int sel = blockIdx.y >> 1, dhalf = blockIdx.y & 1, ot0 = dhalf * 64;
  const int b = blockIdx.z >> 1, s = blockIdx.z & 1;
  const int C = s ? CL_ : CH_;
  const float* Wm = s ? (sel == 0 ? g.W0l : sel == 1 ? g.W1l : g.W2l)
                      : (sel == 0 ? g.W0h : sel == 1 ? g.W1h : g.W2h);
  const short* Bs = (s ? g.BsL : g.BsH) + (size_t)b * N_ * C;

  f32x4 acc[4];
  #pragma unroll
  for (int i = 0; i < 4; ++i) acc[i] = (f32x4){0.f, 0.f, 0.f, 0.f};

  for (int c0 = 0; c0 < C; c0 += 64) {
    __syncthreads();
    {
      int o = tid >> 2, cq = tid & 3;
      const float* wp = Wm + (size_t)(ot0 + o) * C + c0 + cq * 16;
      float4 fa = *(const float4*)(wp + 0);
      float4 fb = *(const float4*)(wp + 4);
      float4 fc = *(const float4*)(wp + 8);
      float4 fd = *(const float4*)(wp + 12);
      short8 v0 = { f2bf(fa.x), f2bf(fa.y), f2bf(fa.z), f2bf(fa.w),
                    f2bf(fb.x), f2bf(fb.y), f2bf(fb.z), f2bf(fb.w) };
      short8 v1 = { f2bf(fc.x), f2bf(fc.y), f2bf(fc.z), f2bf(fc.w),
                    f2bf(fd.x), f2bf(fd.y), f2bf(fd.z), f2bf(fd.w) };
      int g0 = cq * 2;
      *(short8*)(AB + o * 128 + (((g0) ^ (o & 7)) * 16)) = v0;
      *(short8*)(AB + o * 128 + (((g0 + 1) ^ (o & 7)) * 16)) = v1;
    }
    #pragma unroll
    for (int e = 0; e < 2; ++e) {
      int cid = e * 256 + w * 64 + lane;
      int nn = cid >> 3, gs = cid & 7;
      gl_lds16(Bs + (size_t)(n0 + nn) * C + c0 + gs * 8,
               AB + 8192 + e * 4096 + w * 1024 + lane * 16);
    }
    __syncthreads();
    const int orow = w * 16 + m;
    short8 a0 = *(const short8*)(AB + orow * 128 + (((hi) ^ (orow & 7)) * 16));
    short8 a1 = *(const short8*)(AB + orow * 128 + (((4 + hi) ^ (orow & 7)) * 16));
    #pragma unroll
    for (int nf = 0; nf < 4; ++nf) {
      int nrow = nf * 16 + m;
      short8 b0 = *(const short8*)(AB + 8192 + nrow * 128 + (((hi) ^ (nrow & 7)) * 16));
      short8 b1 = *(const short8*)(AB + 8192 + nrow * 128 + (((4 + hi) ^ (nrow & 7)) * 16));
      acc[nf] = __builtin_amdgcn_mfma_f32_16x16x32_bf16(a0, b0, acc[nf], 0, 0, 0);
      acc[nf] = __builtin_amdgcn_mfma_f32_16x16x32_bf16(a1, b1, acc[nf], 0, 0, 0);
    }
  }

  #pragma unroll
  for (int nf = 0; nf < 4; ++nf)
    #pragma unroll
    for (int r = 0; r < 4; ++r)
      Epi[w * 16 + hi * 4 + r][nf * 16 + m] = acc[nf][r];
  __syncthreads();

  if (sel < 2) {
    float sc = (sel == 0) ? g.qscale : 1.f;
    short* QK = (sel == 0 ? (s ? g.QbL : g.QbH) : (s ? g.KbL : g.KbH)) + (size_t)b * N_ * D_;
    short* QKt = (sel == 0 ? (s ? g.QtL : g.QtH) : (s ? g.KtL : g.KtH)) + (size_t)b * N_ * D_;
    const int bx = blockIdx.x;
    #pragma unroll
    for (int e = 0; e < 2; ++e) {
      int u = tid + 256 * e;
      int nn = u >> 3, gl = u & 7;
      short8 v;
      #pragma unroll
      for (int j = 0; j < 8; ++j) v[j] = f2bf(Epi[gl*8 + j][nn] * sc);
      int posb = (dhalf * 8) | ((gl ^ (nn & 7)) & 7);
      *(short8*)(QK + (size_t)(n0 + nn) * D_ + posb * 8) = v;
      int post = (dhalf * 8) | ((gl ^ (bx & 7)) & 7);
      *(short8*)(QKt + (size_t)(nn * 64 + bx) * D_ + post * 8) = v;
    }
  } else {
    short* Vb = (s ? g.VbL : g.VbH) + (size_t)b * D_ * N_;
    #pragma unroll
    for (int e = 0; e < 2; ++e) {
      int u = tid + 256 * e;
      int o = u >> 3, gl = u & 7;
      int d = ot0 + o;
      short8 v;
      #pragma unroll
      for (int j = 0; j < 8; ++j) v[j] = f2bf(Epi[o][gl*8 + j]);
      *(short8*)(Vb + (size_t)d * N_ + n0 + ((gl ^ (d & 7)) * 8)) = v;
    }
  }
}

// ---------------------------------------------------------------------------
// Fused small MFMA flash attention: rows/cols/diag (unchanged).
// ---------------------------------------------------------------------------
struct SmP {
  const short *Qhb, *Qlb, *Khb, *Klb, *Vhb, *Vlb;
  const short *Qht, *Qlt, *Kht, *Klt, *Vht, *Vlt;
  float *Mrl, *Mrh, *Mcl, *Mch, *Mdl, *Mdh;
  const float* alpha;
};

__global__ __launch_bounds__(256, 2)
void attn_sm(SmP p) {
  __shared__ __align__(16) char smem[49152];
  const int tid = threadIdx.x;
  const int lane = tid & 63, w = tid >> 6, m = lane & 15, hi = lane >> 4;

  const int bxg = blockIdx.x;
  int variant, y, bz, qx;
  if (bxg < 256)      { variant = 0; y = bxg & 63;        bz = bxg >> 6;        qx = 0; }
  else if (bxg < 512) { variant = 1; y = (bxg-256) & 63;  bz = (bxg-256) >> 6;  qx = 0; }
  else                { variant = 2; y = 0;               bz = (bxg-512) >> 1;  qx = (bxg-512) & 1; }
  const int b = bz >> 1, pair = bz & 1;
  const int widx = variant;
  const int cwflag = (variant == 2);
  const int qbase = (variant == 2) ? qx * 64 : y * 64;
  const int kcol0 = (variant == 2) ? 0 : y * 64;
  const int Lk = (variant == 2) ? 127 : 64;
  const int lqloc = (variant == 2) ? (qx ? 63 : 64) : 64;

  const short *Qs, *Ks, *Vs;
  if (variant == 1) {
    Qs = pair ? p.Qlt : p.Qht; Ks = pair ? p.Kht : p.Klt; Vs = pair ? p.Vht : p.Vlt;
  } else {
    Qs = pair ? p.Qlb : p.Qhb; Ks = pair ? p.Khb : p.Klb; Vs = pair ? p.Vhb : p.Vlb;
  }
  Qs += (size_t)b * N_ * D_; Ks += (size_t)b * N_ * D_; Vs += (size_t)b * D_ * N_;
  float* Mout;
  if (variant == 0)      Mout = (pair ? p.Mrh : p.Mrl) + (size_t)b * D_ * N_;
  else if (variant == 1) Mout = (pair ? p.Mch : p.Mcl) + (size_t)b * D_ * N_;
  else                   Mout = (pair ? p.Mdh : p.Mdl) + (size_t)b * D_ * 128;

  float a0 = p.alpha[0], a1 = p.alpha[1], a2 = p.alpha[2], a3 = p.alpha[3];
  float am = fmaxf(fmaxf(a0, a1), fmaxf(a2, a3));
  float e0 = __expf(a0-am), e1 = __expf(a1-am), e2 = __expf(a2-am), e3 = __expf(a3-am);
  float wsel = (widx == 0 ? e0 : widx == 1 ? e1 : e2) / (e0 + e1 + e2 + e3);

  auto stageK = [&](int kt) {
    #pragma unroll
    for (int i = 0; i < 4; ++i) {
      int chunk = w * 4 + i;
      gl_lds16(Ks + (size_t)(kcol0 + kt*64) * D_ + chunk * 512 + lane * 8,
               smem + 16384 + chunk * 1024);
    }
  };
  auto stageV = [&](int kt) {
    #pragma unroll
    for (int i = 0; i < 4; ++i) {
      int chunk = w * 4 + i;
      gl_lds16(Vs + (size_t)(chunk*8 + (lane>>3)) * N_ + kcol0 + kt*64 + (lane&7)*8,
               smem + 32768 + chunk * 1024);
    }
  };
  #pragma unroll
  for (int i = 0; i < 4; ++i) {
    int chunk = w * 4 + i;
    gl_lds16(Qs + (size_t)qbase * D_ + chunk * 512 + lane * 8, smem + chunk * 1024);
  }
  stageK(0); stageV(0);
  __syncthreads();

  const int qrow = w * 16 + m;
  short8 qf[4];
  #pragma unroll
  for (int cs = 0; cs < 4; ++cs)
    qf[cs] = *(const short8*)(smem + qrow * 256 + ((cs*64 + hi*16) ^ ((qrow & 7) << 4)));
  __syncthreads();

  f32x4 oacc[8];
  #pragma unroll
  for (int i = 0; i < 8; ++i) oacc[i] = (f32x4){0.f, 0.f, 0.f, 0.f};
  float m_run[4] = {-INFINITY, -INFINITY, -INFINITY, -INFINITY};
  float l_run[4] = {0.f, 0.f, 0.f, 0.f};
  char* const pstrip = smem + w * 2048;
  const int NT = (Lk + 63) >> 6;

  for (int kt = 0; kt < NT; ++kt) {
    const char* Kc = smem + 16384;
    const char* Vc = smem + 32768;
    f32x4 sacc[4];
    #pragma unroll
    for (int kf = 0; kf < 4; ++kf) sacc[kf] = (f32x4){0.f, 0.f, 0.f, 0.f};
    #pragma unroll
    for (int kf = 0; kf < 4; ++kf) {
      const int krow = kf * 16 + m;
      const char* kr = Kc + krow * 256;
      #pragma unroll
      for (int cs = 0; cs < 4; ++cs) {
        short8 kfr = *(const short8*)(kr + ((cs*64 + hi*16) ^ ((krow & 7) << 4)));
        sacc[kf] = __builtin_amdgcn_mfma_f32_16x16x32_bf16(qf[cs], kfr, sacc[kf], 0, 0, 0);
      }
    }
    float cw[4];
    #pragma unroll
    for (int kf = 0; kf < 4; ++kf) {
      if (cwflag) {
        int kg = kt * 64 + kf * 16 + m;
        int dd = kg - 63; dd = dd < 0 ? -dd : dd;
        cw[kf] = (kg < Lk) ? (float)(64 - dd) : 0.f;
      } else cw[kf] = 1.f;
    }
    #pragma unroll
    for (int r = 0; r < 4; ++r) {
      float mt = fmaxf(fmaxf(sacc[0][r], sacc[1][r]), fmaxf(sacc[2][r], sacc[3][r]));
      mt = fmaxf(mt, __shfl_xor(mt, 1));
      mt = fmaxf(mt, __shfl_xor(mt, 2));
      mt = fmaxf(mt, __shfl_xor(mt, 4));
      mt = fmaxf(mt, __shfl_xor(mt, 8));
      float mn = fmaxf(m_run[r], mt);
      float corr = EXP2(m_run[r] - mn);
      m_run[r] = mn;
      const int rl = hi * 4 + r;
      char* prow = pstrip + rl * 128;
      float psum = 0.f;
      #pragma unroll
      for (int kf = 0; kf < 4; ++kf) {
        float pv = cw[kf] * EXP2(sacc[kf][r] - mn);
        psum += pv;
        int kcol = (kf * 16 + m) * 2;
        *(short*)(prow + (kcol ^ ((rl & 7) << 4))) = f2bf(pv);
      }
      psum += __shfl_xor(psum, 1);
      psum += __shfl_xor(psum, 2);
      psum += __shfl_xor(psum, 4);
      psum += __shfl_xor(psum, 8);
      l_run[r] = l_run[r] * corr + psum;
      #pragma unroll
      for (int cf = 0; cf < 8; ++cf) oacc[cf][r] *= corr;
    }
    #pragma unroll
    for (int ks = 0; ks < 2; ++ks) {
      short8 pa = *(const short8*)(pstrip + m * 128 + ((ks*64 + hi*16) ^ ((m & 7) << 4)));
      #pragma unroll
      for (int cf = 0; cf < 8; ++cf) {
        const int crow = cf * 16 + m;
        short8 vf = *(const short8*)(Vc + crow * 128 + ((ks*64 + hi*16) ^ ((crow & 7) << 4)));
        oacc[cf] = __builtin_amdgcn_mfma_f32_16x16x32_bf16(pa, vf, oacc[cf], 0, 0, 0);
      }
    }
    __syncthreads();
    if (kt + 1 < NT) { stageK(kt + 1); stageV(kt + 1); __syncthreads(); }
  }

  float inv[4];
  #pragma unroll
  for (int r = 0; r < 4; ++r) inv[r] = wsel / l_run[r];
  float* Os = (float*)smem;
  #pragma unroll
  for (int cf = 0; cf < 8; ++cf)
    #pragma unroll
    for (int r = 0; r < 4; ++r)
      Os[(cf*16 + m) * 66 + w * 16 + hi * 4 + r] = oacc[cf][r] * inv[r];
  __syncthreads();
  for (int it = 0; it < 32; ++it) {
    int flat = it * 256 + tid;
    int c = flat >> 6, qq = flat & 63;
    if (qq < lqloc) {
      float v = Os[c * 66 + qq];
      if (variant == 0)      Mout[(size_t)c * N_ + qbase + qq] = v;
      else if (variant == 1) Mout[(size_t)c * N_ + qq * 64 + y] = v;
      else                   Mout[c * 128 + qbase + qq] = v;
    }
  }
}

// ---------------------------------------------------------------------------
// Global attention v5: K direct global->register (double-buffered prefetch,
// no K LDS staging) — halves LDS reads AND staging writes. V stays LDS
// (quad 128-key, dbuf). 256 blocks x 512 thr, 8 waves = 2 q-strips x 4-way
// key parity, in-register softmax. LDS: V 2x32KB | merge regions.
// ---------------------------------------------------------------------------
struct GlobalAttnParams {
  const short *Qhb, *Qlb, *Khb, *Klb, *Vhb, *Vlb;
  const float *Mrl, *Mrh, *Mcl, *Mch, *Mdl, *Mdh;
  short *Mtbl, *Mtbh;
  const float* alpha;
};

__global__ __launch_bounds__(512, 1)
void attn_gl_kernel(GlobalAttnParams p) {
  __shared__ __align__(16) char smem[101376];
  const int tid = threadIdx.x;
  const int lane = tid & 63, w = tid >> 6;     // 8 waves
  const int wid = w & 1, gsel = w >> 1;        // q-strip, tile parity 0..3
  const int key = lane & 31, kh = lane >> 5;

  const int bx = blockIdx.x;
  const int xcd = bx & 7, sub = bx >> 3;
  const int pz = xcd >> 1;
  const int b = pz >> 1, pair = pz & 1;
  const int q0 = ((xcd & 1) * 32 + sub) * 64;

  const short* Qb = (pair ? p.Qlb : p.Qhb) + (size_t)b * N_ * D_;
  const short* Kb = (pair ? p.Khb : p.Klb) + (size_t)b * N_ * D_;
  const short* Vb = (pair ? p.Vhb : p.Vlb) + (size_t)b * D_ * N_;
  const float* Mr = (pair ? p.Mrh : p.Mrl) + (size_t)b * D_ * N_;
  const float* Mc = (pair ? p.Mch : p.Mcl) + (size_t)b * D_ * N_;
  const float* Md = (pair ? p.Mdh : p.Mdl) + (size_t)b * D_ * 128;
  short* Mtb = (pair ? p.Mtbh : p.Mtbl) + (size_t)b * N_ * D_;

  float a0 = p.alpha[0], a1 = p.alpha[1], a2 = p.alpha[2], a3 = p.alpha[3];
  float am = fmaxf(fmaxf(a0,a1), fmaxf(a2,a3));
  float e0 = __expf(a0-am), e1 = __expf(a1-am), e2 = __expf(a2-am), e3 = __expf(a3-am);
  const float wsel = e3 / (e0+e1+e2+e3);

  // V quad staging only (32 chunks of 1KB over 8 waves)
  auto stageQuad = [&](int qd) {
    #pragma unroll
    for (int i = 0; i < 4; ++i) {
      int cc = w*4 + i;                      // 0..31
      int d = cc*4 + (lane >> 4);
      int g = lane & 15, kb2 = g >> 3, gg = g & 7;
      gl_lds16(Vb + (size_t)d*N_ + qd*128 + kb2*64 + ((gg ^ (d & 7))*8),
               smem + (qd & 1)*32768 + cc*1024);
    }
  };
  // K fragment: per-lane direct global (row = tile*32+key of [n][d] swizzled)
  auto loadK = [&](int t, short8* kreg) {
    const short* kb = Kb + (size_t)(t*32 + key) * D_;
    #pragma unroll
    for (int fi = 0; fi < 8; ++fi)
      kreg[fi] = *(const short8*)(kb + (((fi*2 + kh) ^ (key & 7)) << 3));
  };

  // Q: per-lane direct global -> regs
  const int qq = wid*32 + key;
  const short* qrow_g = Qb + (size_t)(q0 + qq) * D_;
  short8 qf[8];
  #pragma unroll
  for (int fi = 0; fi < 8; ++fi)
    qf[fi] = *(const short8*)(qrow_g + (((fi*2 + kh) ^ (qq & 7)) << 3));

  short8 kcur[8], knxt[8];
  loadK(gsel, kcur);                         // tile for j=0
  stageQuad(0);

  f32x16 oacc[4];
  #pragma unroll
  for (int d = 0; d < 4; ++d)
    #pragma unroll
    for (int r = 0; r < 16; ++r) oacc[d][r] = 0.f;
  float m_run = -INFINITY, l_run = 0.f;

  const int NQ = N_ / 128;
  for (int j = 0; j < NQ; ++j) {
    __syncthreads();                         // drains vmcnt(0): V quad j + kcur landed
    if (j + 1 < NQ) { stageQuad(j + 1); loadK(4*(j+1) + gsel, knxt); }

    const char* Vc = smem + (j & 1)*32768;

    // ---- S^T = mfma(K, Q): lane owns query qq ----
    f32x16 sacc;
    #pragma unroll
    for (int r = 0; r < 16; ++r) sacc[r] = 0.f;
    __builtin_amdgcn_s_setprio(1);
    #pragma unroll
    for (int fi = 0; fi < 8; ++fi)
      sacc = __builtin_amdgcn_mfma_f32_32x32x16_bf16(kcur[fi], qf[fi], sacc, 0, 0, 0);
    __builtin_amdgcn_s_setprio(0);

    // ---- in-register online softmax ----
    float mt = sacc[0];
    #pragma unroll
    for (int r = 1; r < 16; ++r) mt = fmaxf(mt, sacc[r]);
    { float aa = mt, bb = mt; PLSWAP(aa, bb); mt = fmaxf(aa, bb); }
    if (!__all(mt <= m_run + 8.f)) {
      float mn = fmaxf(m_run, mt);
      float corr = EXP2(m_run - mn);
      m_run = mn;
      l_run *= corr;
      #pragma unroll
      for (int d = 0; d < 4; ++d)
        #pragma unroll
        for (int r = 0; r < 16; ++r) oacc[d][r] *= corr;
    }
    float pv[16];
    float psum = 0.f;
    #pragma unroll
    for (int r = 0; r < 16; ++r) { pv[r] = EXP2(sacc[r] - m_run); psum += pv[r]; }
    { float sa = psum, sb = psum; PLSWAP(sa, sb); psum = sa + sb; }
    l_run += psum;

    union U8 { unsigned u[4]; short8 s; } pf0, pf1;
    {
      unsigned c0, c1, c2, c3;
      CVTPK(c0, pv[0], pv[1]);  CVTPK(c1, pv[2], pv[3]);
      CVTPK(c2, pv[4], pv[5]);  CVTPK(c3, pv[6], pv[7]);
      PLSWAP(c0, c2); PLSWAP(c1, c3);
      pf0.u[0] = c0; pf0.u[1] = c1; pf0.u[2] = c2; pf0.u[3] = c3;
      CVTPK(c0, pv[8],  pv[9]);  CVTPK(c1, pv[10], pv[11]);
      CVTPK(c2, pv[12], pv[13]); CVTPK(c3, pv[14], pv[15]);
      PLSWAP(c0, c2); PLSWAP(c1, c3);
      pf1.u[0] = c0; pf1.u[1] = c1; pf1.u[2] = c2; pf1.u[3] = c3;
    }

    // ---- O^T += mfma(V, P) ----
    __builtin_amdgcn_s_setprio(1);
    #pragma unroll
    for (int d = 0; d < 4; ++d) {
      #pragma unroll
      for (int ks = 0; ks < 2; ++ks) {
        int crow = d*32 + key;
        int gidx = gsel*4 + ks*2 + kh;
        int kb2 = gidx >> 3, gg = gidx & 7;
        short8 vf = *(const short8*)(Vc + crow*256 + kb2*128 + ((gg ^ (key & 7)) << 4));
        oacc[d] = __builtin_amdgcn_mfma_f32_32x32x16_bf16(vf, (ks ? pf1.s : pf0.s), oacc[d], 0, 0, 0);
      }
    }
    __builtin_amdgcn_s_setprio(0);

    if (j + 1 < NQ) {
      #pragma unroll
      for (int fi = 0; fi < 8; ++fi) kcur[fi] = knxt[fi];
    }
  }
  __syncthreads();

  // ---- 4-way parity merge (partials at 0..96K, m/l at 98304) ----
  float* MLbase = (float*)(smem + 98304);
  if (gsel > 0) {
    int idx = (gsel - 1)*2 + wid;
    float* ob = (float*)smem + idx*4096;
    #pragma unroll
    for (int d = 0; d < 4; ++d)
      #pragma unroll
      for (int r = 0; r < 16; ++r)
        ob[(d*16 + r)*64 + lane] = oacc[d][r];
    float* ml = MLbase + idx*128;
    ml[lane] = m_run;
    ml[64 + lane] = l_run;
  }
  __syncthreads();

  float inv = 0.f;
  if (gsel == 0) {
    float mp[3], lp[3];
    float mn = m_run;
    #pragma unroll
    for (int pi = 0; pi < 3; ++pi) {
      const float* ml = MLbase + (pi*2 + wid)*128;
      mp[pi] = ml[lane]; lp[pi] = ml[64 + lane];
      mn = fmaxf(mn, mp[pi]);
    }
    float cA = EXP2(m_run - mn);
    float lt = l_run * cA;
    #pragma unroll
    for (int d = 0; d < 4; ++d)
      #pragma unroll
      for (int r = 0; r < 16; ++r) oacc[d][r] *= cA;
    #pragma unroll
    for (int pi = 0; pi < 3; ++pi) {
      float cp = EXP2(mp[pi] - mn);
      lt += lp[pi] * cp;
      const float* ob = (const float*)smem + (pi*2 + wid)*4096;
      #pragma unroll
      for (int d = 0; d < 4; ++d)
        #pragma unroll
        for (int r = 0; r < 16; ++r)
          oacc[d][r] += ob[(d*16 + r)*64 + lane] * cp;
    }
    inv = wsel / lt;
  }
  __syncthreads();

  float* Os = (float*)smem;
  if (gsel == 0) {
    #pragma unroll
    for (int d = 0; d < 4; ++d)
      #pragma unroll
      for (int r = 0; r < 16; ++r) {
        int dr = d*32 + (r & 3) + 8*(r >> 2) + 4*kh;
        Os[dr*66 + qq] = oacc[d][r] * inv;
      }
  }
  __syncthreads();

  // add rows+cols(+diag) terms, then emit M^T bf16 swizzled
  for (int it = 0; it < 16; ++it) {
    int flat = it*512 + tid;
    int c = flat >> 6, q2 = flat & 63;
    int pos = q0 + q2;
    float add = Mr[(size_t)c*N_ + pos] + Mc[(size_t)c*N_ + pos];
    if (pos < 127) add += Md[c*128 + pos];
    Os[c*66 + q2] += add;
  }
  __syncthreads();
  #pragma unroll
  for (int e = 0; e < 2; ++e) {
    int u = tid + 512*e;
    int nn = u >> 4, gb = u & 15;
    short8 v;
    #pragma unroll
    for (int jj = 0; jj < 8; ++jj) v[jj] = f2bf(Os[(gb*8 + jj)*66 + nn]);
    int pos = (gb & 8) | ((gb ^ (nn & 7)) & 7);
    *(short8*)(Mtb + (size_t)(q0 + nn)*D_ + pos*8) = v;
  }
}

// ---------------------------------------------------------------------------
// Dual-parameter bf16 MFMA GEMM (unchanged).
// ---------------------------------------------------------------------------
struct Gemm2P {
  const float *WA; const short *BA; const float *resA, *biasA; float *outA; short *UtA; int KA, OA;
  const float *WB; const short *BB; const float *resB, *biasB; float *outB; short *UtB; int KB, OB;
  int ysplit, epmode;
};

__global__ __launch_bounds__(256, 4)
void gemm2_bf16(Gemm2P g) {
  __shared__ __align__(16) char AB[16384];
  __shared__ float Epi[64][67];
  const int tid = threadIdx.x;
  const int lane = tid & 63, w = tid >> 6, m = lane & 15, hi = lane >> 4;
  const int n0 = blockIdx.x * 64;
  const int b = blockIdx.z;
  const int yy = blockIdx.y;
  const bool isB = yy >= g.ysplit;
  const int ot0 = (isB ? (yy - g.ysplit) : yy) * 64;
  const float* Wm = isB ? g.WB : g.WA;
  const int K = isB ? g.KB : g.KA;
  const int O = isB ? g.OB : g.OA;
  const short* Bs = (isB ? g.BB : g.BA) + (size_t)b * N_ * K;

  f32x4 acc[4];
  #pragma unroll
  for (int i = 0; i < 4; ++i) acc[i] = (f32x4){0.f, 0.f, 0.f, 0.f};

  for (int c0 = 0; c0 < K; c0 += 64) {
    __syncthreads();
    {
      int o = tid >> 2, cq = tid & 3;
      const float* wp = Wm + (size_t)(ot0 + o) * K + c0 + cq * 16;
      float4 fa = *(const float4*)(wp + 0);
      float4 fb = *(const float4*)(wp + 4);
      float4 fc = *(const float4*)(wp + 8);
      float4 fd = *(const float4*)(wp + 12);
      short8 v0 = { f2bf(fa.x), f2bf(fa.y), f2bf(fa.z), f2bf(fa.w),
                    f2bf(fb.x), f2bf(fb.y), f2bf(fb.z), f2bf(fb.w) };
      short8 v1 = { f2bf(fc.x), f2bf(fc.y), f2bf(fc.z), f2bf(fc.w),
                    f2bf(fd.x), f2bf(fd.y), f2bf(fd.z), f2bf(fd.w) };
      int g0 = cq * 2;
      *(short8*)(AB + o * 128 + (((g0) ^ (o & 7)) * 16)) = v0;
      *(short8*)(AB + o * 128 + (((g0 + 1) ^ (o & 7)) * 16)) = v1;
    }
    #pragma unroll
    for (int e = 0; e < 2; ++e) {
      int cid = e * 256 + w * 64 + lane;
      int nn = cid >> 3, gs = cid & 7;
      gl_lds16(Bs + (size_t)(n0 + nn) * K + c0 + gs * 8,
               AB + 8192 + e * 4096 + w * 1024 + lane * 16);
    }
    __syncthreads();
    const int orow = w * 16 + m;
    short8 a0 = *(const short8*)(AB + orow * 128 + (((hi) ^ (orow & 7)) * 16));
    short8 a1 = *(const short8*)(AB + orow * 128 + (((4 + hi) ^ (orow & 7)) * 16));
    #pragma unroll
    for (int nf = 0; nf < 4; ++nf) {
      int nrow = nf * 16 + m;
      short8 b0 = *(const short8*)(AB + 8192 + nrow * 128 + (((hi) ^ (nrow & 7)) * 16));
      short8 b1 = *(const short8*)(AB + 8192 + nrow * 128 + (((4 + hi) ^ (nrow & 7)) * 16));
      acc[nf] = __builtin_amdgcn_mfma_f32_16x16x32_bf16(a0, b0, acc[nf], 0, 0, 0);
      acc[nf] = __builtin_amdgcn_mfma_f32_16x16x32_bf16(a1, b1, acc[nf], 0, 0, 0);
    }
  }

  #pragma unroll
  for (int nf = 0; nf < 4; ++nf)
    #pragma unroll
    for (int r = 0; r < 4; ++r)
      Epi[w * 16 + hi * 4 + r][nf * 16 + m] = acc[nf][r];
  __syncthreads();

  if (g.epmode == 1) {
    const float* res = (isB ? g.resB : g.resA) + (size_t)b * O * N_;
    const float* bias = isB ? g.biasB : g.biasA;
    short* Ut = (isB ? g.UtB : g.UtA) + (size_t)b * N_ * O;
    #pragma unroll
    for (int e = 0; e < 2; ++e) {
      int nn = tid & 63;
      int gl = (tid >> 6) + e * 4;
      int ob = ot0 + gl * 8;
      short8 v;
      #pragma unroll
      for (int j = 0; j < 8; ++j)
        v[j] = f2bf(Epi[gl*8 + j][nn] + res[(size_t)(ob + j) * N_ + n0 + nn] + bias[ob + j]);
      int gout = (ot0 >> 3) + gl;
      int pos = (gout & ~7) | ((gout ^ (nn & 7)) & 7);
      *(short8*)(Ut + (size_t)(n0 + nn) * O + pos * 8) = v;
    }
  } else {
    const float* bias = isB ? g.biasB : g.biasA;
    float* outF = isB ? g.outB : g.outA;
    int o = tid >> 2, nq = tid & 3;
    float bv = bias[ot0 + o];
    float* dst = outF + (size_t)b * O * N_ + (size_t)(ot0 + o) * N_ + n0 + nq * 16;
    #pragma unroll
    for (int q4 = 0; q4 < 4; ++q4) {
      float4 vv = { Epi[o][nq*16 + q4*4 + 0] + bv, Epi[o][nq*16 + q4*4 + 1] + bv,
                    Epi[o][nq*16 + q4*4 + 2] + bv, Epi[o][nq*16 + q4*4 + 3] + bv };
      *(float4*)(dst + q4 * 4) = vv;
    }
  }
}

// ---------------------------------------------------------------------------
extern "C" void kernel_launch(void* const* d_in, const int* in_sizes, int n_in,
                              void* d_out, int out_size, void* d_ws, size_t ws_size,
                              hipStream_t stream) {
  (void)in_sizes; (void)n_in; (void)out_size; (void)ws_size;
  const float* ll  = (const float*)d_in[0];
  const float* hf  = (const float*)d_in[1];
  const float* Wqh = (const float*)d_in[2];
  const float* Wkh = (const float*)d_in[3];
  const float* Wvh = (const float*)d_in[4];
  const float* Wql = (const float*)d_in[5];
  const float* Wkl = (const float*)d_in[6];
  const float* Wvl = (const float*)d_in[7];
  const float* Wph = (const float*)d_in[8];
  const float* bph = (const float*)d_in[9];
  const float* Wpl = (const float*)d_in[10];
  const float* bpl = (const float*)d_in[11];
  const float* Wah = (const float*)d_in[12];
  const float* bah = (const float*)d_in[13];
  const float* Wal = (const float*)d_in[14];
  const float* bal = (const float*)d_in[15];
  const float* alpha = (const float*)d_in[16];

  float* ws = (float*)d_ws;
  const size_t BDN = (size_t)B_ * D_ * N_;
  float* Mrl = ws;
  float* Mrh = Mrl + BDN;
  float* Mcl = Mrh + BDN;
  float* Mch = Mcl + BDN;
  float* Mdl = Mch + BDN;
  float* Mdh = Mdl + (size_t)B_ * D_ * 128;
  short* sp = (short*)(Mdh + (size_t)B_ * D_ * 128);
  short* Qhb = sp;           sp += BDN;
  short* Qlb = sp;           sp += BDN;
  short* Khb = sp;           sp += BDN;
  short* Klb = sp;           sp += BDN;
  short* Vhb = sp;           sp += BDN;
  short* Vlb = sp;           sp += BDN;
  short* Qht = sp;           sp += BDN;
  short* Qlt = sp;           sp += BDN;
  short* Kht = sp;           sp += BDN;
  short* Klt = sp;           sp += BDN;
  short* Vht = sp;           sp += BDN;
  short* Vlt = sp;           sp += BDN;
  short* hfT = sp;           sp += (size_t)B_ * N_ * CH_;
  short* llT = sp;           sp += (size_t)B_ * N_ * CL_;
  short* Mtbl = Qht;
  short* Mtbh = Qlt;
  short* Utl  = Kht;
  short* Uth  = Klt;

  dim3 blk(256, 1, 1);
  const float qscale = (float)(0.08838834764831845 * 1.4426950408889634);
  float* out = (float*)d_out;

  // 1) transpose+convert inputs (both streams, one launch)
  xt_kernel<<<dim3(N_/64, B_, 2), blk, 0, stream>>>(hf, ll, hfT, llT);

  // 2) fused QKV MFMA GEMMs (both streams, one launch)
  QkvP qp{Wqh, Wkh, Wvh, Wql, Wkl, Wvl, hfT, llT,
          Qhb, Khb, Vhb, Qht, Kht, Qlb, Klb, Vlb, Qlt, Klt, qscale};
  qkv_kernel<<<dim3(N_/64, 6, 2*B_), blk, 0, stream>>>(qp);

  // 3) image-transposed V copies for cols attention
  vt_kernel<<<dim3(64, 2), blk, 0, stream>>>(Vhb, Vlb, Vht, Vlt);

  // 4) fused rows+cols+diag attention (independent stores to Mr/Mc/Md)
  SmP smp{Qhb, Qlb, Khb, Klb, Vhb, Vlb, Qht, Qlt, Kht, Klt, Vht, Vlt,
          Mrl, Mrh, Mcl, Mch, Mdl, Mdh, alpha};
  attn_sm<<<dim3(520, 1, 1), blk, 0, stream>>>(smp);

  // 5) global attention (sums Mr+Mc+Md, emits M^T bf16)
  GlobalAttnParams gp{Qhb, Qlb, Khb, Klb, Vhb, Vlb,
                      Mrl, Mrh, Mcl, Mch, Mdl, Mdh, Mtbl, Mtbh, alpha};
  attn_gl_kernel<<<dim3(256, 1, 1), dim3(512,1,1), 0, stream>>>(gp);

  // 6) U = x + Wp @ M + bp  (both streams, one launch; emit U^T bf16)
  Gemm2P wp{Wpl, Mtbl, ll, bpl, nullptr, Utl, D_, CL_,
            Wph, Mtbh, hf, bph, nullptr, Uth, D_, CH_, 1, 1};
  gemm2_bf16<<<dim3(N_/64, 4, B_), blk, 0, stream>>>(wp);

  // 7) out = Wa @ U + ba  (both streams, one launch)
  Gemm2P wa{Wal, Utl, nullptr, bal, out, nullptr, CL_, CL_,
            Wah, Uth, nullptr, bah, out + (size_t)B_*CL_*N_, nullptr, CH_, CH_, 1, 2};
  gemm2_bf16<<<dim3(N_/64, 4, B_), blk, 0, stream>>>(wa);
}

// Round 13
// 119.283 us; speedup vs baseline: 1.0756x; 1.0756x over previous
//
#include <hip/hip_runtime.h>
#include <math.h>

#define N_  4096
#define D_  128
#define B_  2
#define CL_ 64
#define CH_ 192

typedef __attribute__((ext_vector_type(8))) short short8;
typedef __attribute__((ext_vector_type(4))) float f32x4;
typedef __attribute__((ext_vector_type(16))) float f32x16;

#if __has_builtin(__builtin_amdgcn_exp2f)
#define EXP2(x) __builtin_amdgcn_exp2f(x)
#else
#define EXP2(x) exp2f(x)
#endif

__device__ __forceinline__ short f2bf(float x) {
  union { float f; unsigned u; } v; v.f = x;
  unsigned r = v.u + 0x7FFFu + ((v.u >> 16) & 1u);
  return (short)(r >> 16);
}

typedef __attribute__((address_space(1))) const void gv_t;
typedef __attribute__((address_space(3))) void sv_t;
__device__ __forceinline__ void gl_lds16(const void* g, void* l) {
  __builtin_amdgcn_global_load_lds((gv_t*)g, (sv_t*)l, 16, 0, 0);
}

#define CVTPK(d, lo, hi) asm("v_cvt_pk_bf16_f32 %0, %1, %2" : "=v"(d) : "v"(lo), "v"(hi))
#define PLSWAP(a, b) asm("v_permlane32_swap_b32 %0, %1" : "+v"(a), "+v"(b))

// ---------------------------------------------------------------------------
// Vt: Vb bf16 [d][n] -> image-transposed Vt [d][n'] (n' = w*64+h), same swizzle.
// ---------------------------------------------------------------------------
__global__ __launch_bounds__(256)
void vt_kernel(const short* __restrict__ Vhb, const short* __restrict__ Vlb,
               short* __restrict__ Vht, short* __restrict__ Vlt) {
  __shared__ short rowbuf[4 * 4096];
  const int tid = threadIdx.x;
  const int lane = tid & 63, w = tid >> 6;
  const short* src = blockIdx.y ? Vlb : Vhb;
  short* dst = blockIdx.y ? Vlt : Vht;
  const int r0 = blockIdx.x * 4;
  #pragma unroll
  for (int i = 0; i < 8; ++i) {
    int idx = i * 256 + w * 64 + lane;
    int row = idx >> 9, g = idx & 511;
    gl_lds16(src + (size_t)(r0 + row) * N_ + g * 8,
             (char*)rowbuf + i * 4096 + w * 1024 + lane * 16);
  }
  __syncthreads();
  const int rw = r0 + w, d7 = rw & 7;
  const short* rb = rowbuf + w * 4096;
  const int w0 = (lane & 7) * 8, h0 = (lane >> 3) * 8;
  short8 rr[8];
  #pragma unroll
  for (int j = 0; j < 8; ++j)
    rr[j] = *(const short8*)(rb + (h0 + j) * 64 + (((w0 >> 3) ^ d7) * 8));
  #pragma unroll
  for (int i = 0; i < 8; ++i) {
    short8 o;
    #pragma unroll
    for (int j = 0; j < 8; ++j) o[j] = rr[j][i];
    *(short8*)(dst + (size_t)rw * N_ + (w0 + i) * 64 + (((h0 >> 3) ^ d7) * 8)) = o;
  }
}

// ---------------------------------------------------------------------------
// Fused QKV MFMA GEMM with INLINE X transpose (xt fused in).
// Builds persistent Bt [64n][C] bf16 (swizzled) in LDS from f32 X, then
// K-loop reads B frags from Bt directly (no per-step B staging).
// grid: (64, 6, 2B). y: sel=y>>1 (Q/K/V), dhalf=y&1. z: b=z>>1, s=z&1.
// ---------------------------------------------------------------------------
struct QkvP {
  const float *W0h, *W1h, *W2h, *W0l, *W1l, *W2l;
  const float *Xh, *Xl;
  short *QbH, *KbH, *VbH, *QtH, *KtH;
  short *QbL, *KbL, *VbL, *QtL, *KtL;
  float qscale;
};

__global__ __launch_bounds__(256, 2)
void qkv_kernel(QkvP g) {
  __shared__ __align__(16) char BT[24576];    // Bt [64][C<=192] bf16 swizzled
  __shared__ __align__(16) char AS[8192];     // A stage (64 o-rows x 64 k)
  __shared__ __align__(16) float Ls[64][67];  // f32 chunk; reused as Epi
  const int tid = threadIdx.x;
  const int lane = tid & 63, w = tid >> 6, m = lane & 15, hi = lane >> 4;
  const int n0 = blockIdx.x * 64;
  const int sel = blockIdx.y >> 1, dhalf = blockIdx.y & 1, ot0 = dhalf * 64;
  const int b = blockIdx.z >> 1, s = blockIdx.z & 1;
  const int C = s ? CL_ : CH_;
  const float* Wm = s ? (sel == 0 ? g.W0l : sel == 1 ? g.W1l : g.W2l)
                      : (sel == 0 ? g.W0h : sel == 1 ? g.W1h : g.W2h);
  const float* Xs = (s ? g.Xl : g.Xh) + (size_t)b * C * N_;
  const int C2 = C * 2;

  // ---- build Bt: [64n][C] bf16, granule ^(nn&7) within each 64-elem window
  for (int cc = 0; cc < C; cc += 64) {
    #pragma unroll
    for (int r = 0; r < 16; ++r) {
      int flat = r * 256 + tid;
      int c = flat >> 6, nn = flat & 63;
      Ls[c][nn] = Xs[(size_t)(cc + c) * N_ + n0 + nn];
    }
    __syncthreads();
    #pragma unroll
    for (int e = 0; e < 2; ++e) {
      int u = e * 256 + tid;
      int nn = u >> 3, gl = u & 7;
      short8 v;
      #pragma unroll
      for (int j = 0; j < 8; ++j) v[j] = f2bf(Ls[gl*8 + j][nn]);
      int pos = (gl ^ (nn & 7)) & 7;
      *(short8*)(BT + nn * C2 + cc * 2 + pos * 16) = v;
    }
    __syncthreads();
  }

  f32x4 acc[4];
  #pragma unroll
  for (int i = 0; i < 4; ++i) acc[i] = (f32x4){0.f, 0.f, 0.f, 0.f};

  for (int c0 = 0; c0 < C; c0 += 64) {
    __syncthreads();
    {   // stage A (f32 -> bf16, swizzled ^(o&7))
      int o = tid >> 2, cq = tid & 3;
      const float* wp = Wm + (size_t)(ot0 + o) * C + c0 + cq * 16;
      float4 fa = *(const float4*)(wp + 0);
      float4 fb = *(const float4*)(wp + 4);
      float4 fc = *(const float4*)(wp + 8);
      float4 fd = *(const float4*)(wp + 12);
      short8 v0 = { f2bf(fa.x), f2bf(fa.y), f2bf(fa.z), f2bf(fa.w),
                    f2bf(fb.x), f2bf(fb.y), f2bf(fb.z), f2bf(fb.w) };
      short8 v1 = { f2bf(fc.x), f2bf(fc.y), f2bf(fc.z), f2bf(fc.w),
                    f2bf(fd.x), f2bf(fd.y), f2bf(fd.z), f2bf(fd.w) };
      int g0 = cq * 2;
      *(short8*)(AS + o * 128 + (((g0) ^ (o & 7)) * 16)) = v0;
      *(short8*)(AS + o * 128 + (((g0 + 1) ^ (o & 7)) * 16)) = v1;
    }
    __syncthreads();
    const int orow = w * 16 + m;
    short8 a0 = *(const short8*)(AS + orow * 128 + (((hi) ^ (orow & 7)) * 16));
    short8 a1 = *(const short8*)(AS + orow * 128 + (((4 + hi) ^ (orow & 7)) * 16));
    #pragma unroll
    for (int nf = 0; nf < 4; ++nf) {
      int nrow = nf * 16 + m;
      const char* brow = BT + nrow * C2 + c0 * 2;
      short8 b0 = *(const short8*)(brow + (((hi) ^ (nrow & 7)) * 16));
      short8 b1 = *(const short8*)(brow + (((4 + hi) ^ (nrow & 7)) * 16));
      acc[nf] = __builtin_amdgcn_mfma_f32_16x16x32_bf16(a0, b0, acc[nf], 0, 0, 0);
      acc[nf] = __builtin_amdgcn_mfma_f32_16x16x32_bf16(a1, b1, acc[nf], 0, 0, 0);
    }
  }

  __syncthreads();
  #pragma unroll
  for (int nf = 0; nf < 4; ++nf)
    #pragma unroll
    for (int r = 0; r < 4; ++r)
      Ls[w * 16 + hi * 4 + r][nf * 16 + m] = acc[nf][r];   // Epi = Ls region
  __syncthreads();

  if (sel < 2) {
    float sc = (sel == 0) ? g.qscale : 1.f;
    short* QK = (sel == 0 ? (s ? g.QbL : g.QbH) : (s ? g.KbL : g.KbH)) + (size_t)b * N_ * D_;
    short* QKt = (sel == 0 ? (s ? g.QtL : g.QtH) : (s ? g.KtL : g.KtH)) + (size_t)b * N_ * D_;
    const int bx = blockIdx.x;
    #pragma unroll
    for (int e = 0; e < 2; ++e) {
      int u = tid + 256 * e;
      int nn = u >> 3, gl = u & 7;
      short8 v;
      #pragma unroll
      for (int j = 0; j < 8; ++j) v[j] = f2bf(Ls[gl*8 + j][nn] * sc);
      int posb = (dhalf * 8) | ((gl ^ (nn & 7)) & 7);
      *(short8*)(QK + (size_t)(n0 + nn) * D_ + posb * 8) = v;
      int post = (dhalf * 8) | ((gl ^ (bx & 7)) & 7);
      *(short8*)(QKt + (size_t)(nn * 64 + bx) * D_ + post * 8) = v;
    }
  } else {
    short* Vb = (s ? g.VbL : g.VbH) + (size_t)b * D_ * N_;
    #pragma unroll
    for (int e = 0; e < 2; ++e) {
      int u = tid + 256 * e;
      int o = u >> 3, gl = u & 7;
      int d = ot0 + o;
      short8 v;
      #pragma unroll
      for (int j = 0; j < 8; ++j) v[j] = f2bf(Ls[o][gl*8 + j]);
      *(short8*)(Vb + (size_t)d * N_ + n0 + ((gl ^ (d & 7)) * 8)) = v;
    }
  }
}

// ---------------------------------------------------------------------------
// Fused small MFMA flash attention: rows/cols/diag (unchanged).
// ---------------------------------------------------------------------------
struct SmP {
  const short *Qhb, *Qlb, *Khb, *Klb, *Vhb, *Vlb;
  const short *Qht, *Qlt, *Kht, *Klt, *Vht, *Vlt;
  float *Mrl, *Mrh, *Mcl, *Mch, *Mdl, *Mdh;
  const float* alpha;
};

__global__ __launch_bounds__(256, 2)
void attn_sm(SmP p) {
  __shared__ __align__(16) char smem[49152];
  const int tid = threadIdx.x;
  const int lane = tid & 63, w = tid >> 6, m = lane & 15, hi = lane >> 4;

  const int bxg = blockIdx.x;
  int variant, y, bz, qx;
  if (bxg < 256)      { variant = 0; y = bxg & 63;        bz = bxg >> 6;        qx = 0; }
  else if (bxg < 512) { variant = 1; y = (bxg-256) & 63;  bz = (bxg-256) >> 6;  qx = 0; }
  else                { variant = 2; y = 0;               bz = (bxg-512) >> 1;  qx = (bxg-512) & 1; }
  const int b = bz >> 1, pair = bz & 1;
  const int widx = variant;
  const int cwflag = (variant == 2);
  const int qbase = (variant == 2) ? qx * 64 : y * 64;
  const int kcol0 = (variant == 2) ? 0 : y * 64;
  const int Lk = (variant == 2) ? 127 : 64;
  const int lqloc = (variant == 2) ? (qx ? 63 : 64) : 64;

  const short *Qs, *Ks, *Vs;
  if (variant == 1) {
    Qs = pair ? p.Qlt : p.Qht; Ks = pair ? p.Kht : p.Klt; Vs = pair ? p.Vht : p.Vlt;
  } else {
    Qs = pair ? p.Qlb : p.Qhb; Ks = pair ? p.Khb : p.Klb; Vs = pair ? p.Vhb : p.Vlb;
  }
  Qs += (size_t)b * N_ * D_; Ks += (size_t)b * N_ * D_; Vs += (size_t)b * D_ * N_;
  float* Mout;
  if (variant == 0)      Mout = (pair ? p.Mrh : p.Mrl) + (size_t)b * D_ * N_;
  else if (variant == 1) Mout = (pair ? p.Mch : p.Mcl) + (size_t)b * D_ * N_;
  else                   Mout = (pair ? p.Mdh : p.Mdl) + (size_t)b * D_ * 128;

  float a0 = p.alpha[0], a1 = p.alpha[1], a2 = p.alpha[2], a3 = p.alpha[3];
  float am = fmaxf(fmaxf(a0, a1), fmaxf(a2, a3));
  float e0 = __expf(a0-am), e1 = __expf(a1-am), e2 = __expf(a2-am), e3 = __expf(a3-am);
  float wsel = (widx == 0 ? e0 : widx == 1 ? e1 : e2) / (e0 + e1 + e2 + e3);

  auto stageK = [&](int kt) {
    #pragma unroll
    for (int i = 0; i < 4; ++i) {
      int chunk = w * 4 + i;
      gl_lds16(Ks + (size_t)(kcol0 + kt*64) * D_ + chunk * 512 + lane * 8,
               smem + 16384 + chunk * 1024);
    }
  };
  auto stageV = [&](int kt) {
    #pragma unroll
    for (int i = 0; i < 4; ++i) {
      int chunk = w * 4 + i;
      gl_lds16(Vs + (size_t)(chunk*8 + (lane>>3)) * N_ + kcol0 + kt*64 + (lane&7)*8,
               smem + 32768 + chunk * 1024);
    }
  };
  #pragma unroll
  for (int i = 0; i < 4; ++i) {
    int chunk = w * 4 + i;
    gl_lds16(Qs + (size_t)qbase * D_ + chunk * 512 + lane * 8, smem + chunk * 1024);
  }
  stageK(0); stageV(0);
  __syncthreads();

  const int qrow = w * 16 + m;
  short8 qf[4];
  #pragma unroll
  for (int cs = 0; cs < 4; ++cs)
    qf[cs] = *(const short8*)(smem + qrow * 256 + ((cs*64 + hi*16) ^ ((qrow & 7) << 4)));
  __syncthreads();

  f32x4 oacc[8];
  #pragma unroll
  for (int i = 0; i < 8; ++i) oacc[i] = (f32x4){0.f, 0.f, 0.f, 0.f};
  float m_run[4] = {-INFINITY, -INFINITY, -INFINITY, -INFINITY};
  float l_run[4] = {0.f, 0.f, 0.f, 0.f};
  char* const pstrip = smem + w * 2048;
  const int NT = (Lk + 63) >> 6;

  for (int kt = 0; kt < NT; ++kt) {
    const char* Kc = smem + 16384;
    const char* Vc = smem + 32768;
    f32x4 sacc[4];
    #pragma unroll
    for (int kf = 0; kf < 4; ++kf) sacc[kf] = (f32x4){0.f, 0.f, 0.f, 0.f};
    #pragma unroll
    for (int kf = 0; kf < 4; ++kf) {
      const int krow = kf * 16 + m;
      const char* kr = Kc + krow * 256;
      #pragma unroll
      for (int cs = 0; cs < 4; ++cs) {
        short8 kfr = *(const short8*)(kr + ((cs*64 + hi*16) ^ ((krow & 7) << 4)));
        sacc[kf] = __builtin_amdgcn_mfma_f32_16x16x32_bf16(qf[cs], kfr, sacc[kf], 0, 0, 0);
      }
    }
    float cw[4];
    #pragma unroll
    for (int kf = 0; kf < 4; ++kf) {
      if (cwflag) {
        int kg = kt * 64 + kf * 16 + m;
        int dd = kg - 63; dd = dd < 0 ? -dd : dd;
        cw[kf] = (kg < Lk) ? (float)(64 - dd) : 0.f;
      } else cw[kf] = 1.f;
    }
    #pragma unroll
    for (int r = 0; r < 4; ++r) {
      float mt = fmaxf(fmaxf(sacc[0][r], sacc[1][r]), fmaxf(sacc[2][r], sacc[3][r]));
      mt = fmaxf(mt, __shfl_xor(mt, 1));
      mt = fmaxf(mt, __shfl_xor(mt, 2));
      mt = fmaxf(mt, __shfl_xor(mt, 4));
      mt = fmaxf(mt, __shfl_xor(mt, 8));
      float mn = fmaxf(m_run[r], mt);
      float corr = EXP2(m_run[r] - mn);
      m_run[r] = mn;
      const int rl = hi * 4 + r;
      char* prow = pstrip + rl * 128;
      float psum = 0.f;
      #pragma unroll
      for (int kf = 0; kf < 4; ++kf) {
        float pv = cw[kf] * EXP2(sacc[kf][r] - mn);
        psum += pv;
        int kcol = (kf * 16 + m) * 2;
        *(short*)(prow + (kcol ^ ((rl & 7) << 4))) = f2bf(pv);
      }
      psum += __shfl_xor(psum, 1);
      psum += __shfl_xor(psum, 2);
      psum += __shfl_xor(psum, 4);
      psum += __shfl_xor(psum, 8);
      l_run[r] = l_run[r] * corr + psum;
      #pragma unroll
      for (int cf = 0; cf < 8; ++cf) oacc[cf][r] *= corr;
    }
    #pragma unroll
    for (int ks = 0; ks < 2; ++ks) {
      short8 pa = *(const short8*)(pstrip + m * 128 + ((ks*64 + hi*16) ^ ((m & 7) << 4)));
      #pragma unroll
      for (int cf = 0; cf < 8; ++cf) {
        const int crow = cf * 16 + m;
        short8 vf = *(const short8*)(Vc + crow * 128 + ((ks*64 + hi*16) ^ ((crow & 7) << 4)));
        oacc[cf] = __builtin_amdgcn_mfma_f32_16x16x32_bf16(pa, vf, oacc[cf], 0, 0, 0);
      }
    }
    __syncthreads();
    if (kt + 1 < NT) { stageK(kt + 1); stageV(kt + 1); __syncthreads(); }
  }

  float inv[4];
  #pragma unroll
  for (int r = 0; r < 4; ++r) inv[r] = wsel / l_run[r];
  float* Os = (float*)smem;
  #pragma unroll
  for (int cf = 0; cf < 8; ++cf)
    #pragma unroll
    for (int r = 0; r < 4; ++r)
      Os[(cf*16 + m) * 66 + w * 16 + hi * 4 + r] = oacc[cf][r] * inv[r];
  __syncthreads();
  for (int it = 0; it < 32; ++it) {
    int flat = it * 256 + tid;
    int c = flat >> 6, qq = flat & 63;
    if (qq < lqloc) {
      float v = Os[c * 66 + qq];
      if (variant == 0)      Mout[(size_t)c * N_ + qbase + qq] = v;
      else if (variant == 1) Mout[(size_t)c * N_ + qq * 64 + y] = v;
      else                   Mout[c * 128 + qbase + qq] = v;
    }
  }
}

// ---------------------------------------------------------------------------
// Global attention v4 (round-11 revert): 256 blocks x 512 thr, 8 waves =
// 2 q-strips x 4-way key parity, in-register softmax, quad-tile dbuf staging
// (K 2x32KB + V 2x32KB). Epilogue sums Mr+Mc(+Md), emits M^T bf16.
// ---------------------------------------------------------------------------
#define GVQ 65536

struct GlobalAttnParams {
  const short *Qhb, *Qlb, *Khb, *Klb, *Vhb, *Vlb;
  const float *Mrl, *Mrh, *Mcl, *Mch, *Mdl, *Mdh;
  short *Mtbl, *Mtbh;
  const float* alpha;
};

__global__ __launch_bounds__(512, 1)
void attn_gl_kernel(GlobalAttnParams p) {
  __shared__ __align__(16) char smem[131072];
  const int tid = threadIdx.x;
  const int lane = tid & 63, w = tid >> 6;     // 8 waves
  const int wid = w & 1, gsel = w >> 1;        // q-strip, tile parity 0..3
  const int key = lane & 31, kh = lane >> 5;

  const int bx = blockIdx.x;
  const int xcd = bx & 7, sub = bx >> 3;
  const int pz = xcd >> 1;
  const int b = pz >> 1, pair = pz & 1;
  const int q0 = ((xcd & 1) * 32 + sub) * 64;

  const short* Qb = (pair ? p.Qlb : p.Qhb) + (size_t)b * N_ * D_;
  const short* Kb = (pair ? p.Khb : p.Klb) + (size_t)b * N_ * D_;
  const short* Vb = (pair ? p.Vhb : p.Vlb) + (size_t)b * D_ * N_;
  const float* Mr = (pair ? p.Mrh : p.Mrl) + (size_t)b * D_ * N_;
  const float* Mc = (pair ? p.Mch : p.Mcl) + (size_t)b * D_ * N_;
  const float* Md = (pair ? p.Mdh : p.Mdl) + (size_t)b * D_ * 128;
  short* Mtb = (pair ? p.Mtbh : p.Mtbl) + (size_t)b * N_ * D_;

  float a0 = p.alpha[0], a1 = p.alpha[1], a2 = p.alpha[2], a3 = p.alpha[3];
  float am = fmaxf(fmaxf(a0,a1), fmaxf(a2,a3));
  float e0 = __expf(a0-am), e1 = __expf(a1-am), e2 = __expf(a2-am), e3 = __expf(a3-am);
  const float wsel = e3 / (e0+e1+e2+e3);

  auto stageQuad = [&](int qd) {
    #pragma unroll
    for (int i = 0; i < 8; ++i) {
      int c = w*8 + i;
      if (c < 32) {
        int tk = c >> 3, ck = c & 7;
        gl_lds16(Kb + (size_t)((4*qd + tk)*32 + ck*4)*D_ + lane*8,
                 smem + (qd & 1)*32768 + tk*8192 + ck*1024);
      } else {
        int cc = c - 32;
        int d = cc*4 + (lane >> 4);
        int g = lane & 15, kb2 = g >> 3, gg = g & 7;
        gl_lds16(Vb + (size_t)d*N_ + qd*128 + kb2*64 + ((gg ^ (d & 7))*8),
                 smem + GVQ + (qd & 1)*32768 + cc*1024);
      }
    }
  };

  const int qq = wid*32 + key;
  const short* qrow_g = Qb + (size_t)(q0 + qq) * D_;
  short8 qf[8];
  #pragma unroll
  for (int fi = 0; fi < 8; ++fi)
    qf[fi] = *(const short8*)(qrow_g + (((fi*2 + kh) ^ (qq & 7)) << 3));

  stageQuad(0);

  f32x16 oacc[4];
  #pragma unroll
  for (int d = 0; d < 4; ++d)
    #pragma unroll
    for (int r = 0; r < 16; ++r) oacc[d][r] = 0.f;
  float m_run = -INFINITY, l_run = 0.f;

  const int NQ = N_ / 128;
  for (int j = 0; j < NQ; ++j) {
    __syncthreads();
    if (j + 1 < NQ) stageQuad(j + 1);

    const char* Kc = smem + (j & 1)*32768 + gsel*8192;
    const char* Vc = smem + GVQ + (j & 1)*32768;

    f32x16 sacc;
    #pragma unroll
    for (int r = 0; r < 16; ++r) sacc[r] = 0.f;
    __builtin_amdgcn_s_setprio(1);
    #pragma unroll
    for (int fi = 0; fi < 8; ++fi) {
      short8 kf = *(const short8*)(Kc + key*256 + (((fi*2 + kh) ^ (key & 7)) << 4));
      sacc = __builtin_amdgcn_mfma_f32_32x32x16_bf16(kf, qf[fi], sacc, 0, 0, 0);
    }
    __builtin_amdgcn_s_setprio(0);

    float mt = sacc[0];
    #pragma unroll
    for (int r = 1; r < 16; ++r) mt = fmaxf(mt, sacc[r]);
    { float aa = mt, bb = mt; PLSWAP(aa, bb); mt = fmaxf(aa, bb); }
    if (!__all(mt <= m_run + 8.f)) {
      float mn = fmaxf(m_run, mt);
      float corr = EXP2(m_run - mn);
      m_run = mn;
      l_run *= corr;
      #pragma unroll
      for (int d = 0; d < 4; ++d)
        #pragma unroll
        for (int r = 0; r < 16; ++r) oacc[d][r] *= corr;
    }
    float pv[16];
    float psum = 0.f;
    #pragma unroll
    for (int r = 0; r < 16; ++r) { pv[r] = EXP2(sacc[r] - m_run); psum += pv[r]; }
    { float sa = psum, sb = psum; PLSWAP(sa, sb); psum = sa + sb; }
    l_run += psum;

    union U8 { unsigned u[4]; short8 s; } pf0, pf1;
    {
      unsigned c0, c1, c2, c3;
      CVTPK(c0, pv[0], pv[1]);  CVTPK(c1, pv[2], pv[3]);
      CVTPK(c2, pv[4], pv[5]);  CVTPK(c3, pv[6], pv[7]);
      PLSWAP(c0, c2); PLSWAP(c1, c3);
      pf0.u[0] = c0; pf0.u[1] = c1; pf0.u[2] = c2; pf0.u[3] = c3;
      CVTPK(c0, pv[8],  pv[9]);  CVTPK(c1, pv[10], pv[11]);
      CVTPK(c2, pv[12], pv[13]); CVTPK(c3, pv[14], pv[15]);
      PLSWAP(c0, c2); PLSWAP(c1, c3);
      pf1.u[0] = c0; pf1.u[1] = c1; pf1.u[2] = c2; pf1.u[3] = c3;
    }

    __builtin_amdgcn_s_setprio(1);
    #pragma unroll
    for (int d = 0; d < 4; ++d) {
      #pragma unroll
      for (int ks = 0; ks < 2; ++ks) {
        int crow = d*32 + key;
        int gidx = gsel*4 + ks*2 + kh;
        int kb2 = gidx >> 3, gg = gidx & 7;
        short8 vf = *(const short8*)(Vc + crow*256 + kb2*128 + ((gg ^ (key & 7)) << 4));
        oacc[d] = __builtin_amdgcn_mfma_f32_32x32x16_bf16(vf, (ks ? pf1.s : pf0.s), oacc[d], 0, 0, 0);
      }
    }
    __builtin_amdgcn_s_setprio(0);
  }
  __syncthreads();

  // ---- 4-way parity merge ----
  float* MLbase = (float*)(smem + 98304);
  if (gsel > 0) {
    int idx = (gsel - 1)*2 + wid;
    float* ob = (float*)smem + idx*4096;
    #pragma unroll
    for (int d = 0; d < 4; ++d)
      #pragma unroll
      for (int r = 0; r < 16; ++r)
        ob[(d*16 + r)*64 + lane] = oacc[d][r];
    float* ml = MLbase + idx*128;
    ml[lane] = m_run;
    ml[64 + lane] = l_run;
  }
  __syncthreads();

  float inv = 0.f;
  if (gsel == 0) {
    float mp[3], lp[3];
    float mn = m_run;
    #pragma unroll
    for (int pi = 0; pi < 3; ++pi) {
      const float* ml = MLbase + (pi*2 + wid)*128;
      mp[pi] = ml[lane]; lp[pi] = ml[64 + lane];
      mn = fmaxf(mn, mp[pi]);
    }
    float cA = EXP2(m_run - mn);
    float lt = l_run * cA;
    #pragma unroll
    for (int d = 0; d < 4; ++d)
      #pragma unroll
      for (int r = 0; r < 16; ++r) oacc[d][r] *= cA;
    #pragma unroll
    for (int pi = 0; pi < 3; ++pi) {
      float cp = EXP2(mp[pi] - mn);
      lt += lp[pi] * cp;
      const float* ob = (const float*)smem + (pi*2 + wid)*4096;
      #pragma unroll
      for (int d = 0; d < 4; ++d)
        #pragma unroll
        for (int r = 0; r < 16; ++r)
          oacc[d][r] += ob[(d*16 + r)*64 + lane] * cp;
    }
    inv = wsel / lt;
  }
  __syncthreads();

  float* Os = (float*)smem;
  if (gsel == 0) {
    #pragma unroll
    for (int d = 0; d < 4; ++d)
      #pragma unroll
      for (int r = 0; r < 16; ++r) {
        int dr = d*32 + (r & 3) + 8*(r >> 2) + 4*kh;
        Os[dr*66 + qq] = oacc[d][r] * inv;
      }
  }
  __syncthreads();

  for (int it = 0; it < 16; ++it) {
    int flat = it*512 + tid;
    int c = flat >> 6, q2 = flat & 63;
    int pos = q0 + q2;
    float add = Mr[(size_t)c*N_ + pos] + Mc[(size_t)c*N_ + pos];
    if (pos < 127) add += Md[c*128 + pos];
    Os[c*66 + q2] += add;
  }
  __syncthreads();
  #pragma unroll
  for (int e = 0; e < 2; ++e) {
    int u = tid + 512*e;
    int nn = u >> 4, gb = u & 15;
    short8 v;
    #pragma unroll
    for (int jj = 0; jj < 8; ++jj) v[jj] = f2bf(Os[(gb*8 + jj)*66 + nn]);
    int pos = (gb & 8) | ((gb ^ (nn & 7)) & 7);
    *(short8*)(Mtb + (size_t)(q0 + nn)*D_ + pos*8) = v;
  }
}

// ---------------------------------------------------------------------------
// Dual-parameter bf16 MFMA GEMM (unchanged).
// ---------------------------------------------------------------------------
struct Gemm2P {
  const float *WA; const short *BA; const float *resA, *biasA; float *outA; short *UtA; int KA, OA;
  const float *WB; const short *BB; const float *resB, *biasB; float *outB; short *UtB; int KB, OB;
  int ysplit, epmode;
};

__global__ __launch_bounds__(256, 4)
void gemm2_bf16(Gemm2P g) {
  __shared__ __align__(16) char AB[16384];
  __shared__ float Epi[64][67];
  const int tid = threadIdx.x;
  const int lane = tid & 63, w = tid >> 6, m = lane & 15, hi = lane >> 4;
  const int n0 = blockIdx.x * 64;
  const int b = blockIdx.z;
  const int yy = blockIdx.y;
  const bool isB = yy >= g.ysplit;
  const int ot0 = (isB ? (yy - g.ysplit) : yy) * 64;
  const float* Wm = isB ? g.WB : g.WA;
  const int K = isB ? g.KB : g.KA;
  const int O = isB ? g.OB : g.OA;
  const short* Bs = (isB ? g.BB : g.BA) + (size_t)b * N_ * K;

  f32x4 acc[4];
  #pragma unroll
  for (int i = 0; i < 4; ++i) acc[i] = (f32x4){0.f, 0.f, 0.f, 0.f};

  for (int c0 = 0; c0 < K; c0 += 64) {
    __syncthreads();
    {
      int o = tid >> 2, cq = tid & 3;
      const float* wp = Wm + (size_t)(ot0 + o) * K + c0 + cq * 16;
      float4 fa = *(const float4*)(wp + 0);
      float4 fb = *(const float4*)(wp + 4);
      float4 fc = *(const float4*)(wp + 8);
      float4 fd = *(const float4*)(wp + 12);
      short8 v0 = { f2bf(fa.x), f2bf(fa.y), f2bf(fa.z), f2bf(fa.w),
                    f2bf(fb.x), f2bf(fb.y), f2bf(fb.z), f2bf(fb.w) };
      short8 v1 = { f2bf(fc.x), f2bf(fc.y), f2bf(fc.z), f2bf(fc.w),
                    f2bf(fd.x), f2bf(fd.y), f2bf(fd.z), f2bf(fd.w) };
      int g0 = cq * 2;
      *(short8*)(AB + o * 128 + (((g0) ^ (o & 7)) * 16)) = v0;
      *(short8*)(AB + o * 128 + (((g0 + 1) ^ (o & 7)) * 16)) = v1;
    }
    #pragma unroll
    for (int e = 0; e < 2; ++e) {
      int cid = e * 256 + w * 64 + lane;
      int nn = cid >> 3, gs = cid & 7;
      gl_lds16(Bs + (size_t)(n0 + nn) * K + c0 + gs * 8,
               AB + 8192 + e * 4096 + w * 1024 + lane * 16);
    }
    __syncthreads();
    const int orow = w * 16 + m;
    short8 a0 = *(const short8*)(AB + orow * 128 + (((hi) ^ (orow & 7)) * 16));
    short8 a1 = *(const short8*)(AB + orow * 128 + (((4 + hi) ^ (orow & 7)) * 16));
    #pragma unroll
    for (int nf = 0; nf < 4; ++nf) {
      int nrow = nf * 16 + m;
      short8 b0 = *(const short8*)(AB + 8192 + nrow * 128 + (((hi) ^ (nrow & 7)) * 16));
      short8 b1 = *(const short8*)(AB + 8192 + nrow * 128 + (((4 + hi) ^ (nrow & 7)) * 16));
      acc[nf] = __builtin_amdgcn_mfma_f32_16x16x32_bf16(a0, b0, acc[nf], 0, 0, 0);
      acc[nf] = __builtin_amdgcn_mfma_f32_16x16x32_bf16(a1, b1, acc[nf], 0, 0, 0);
    }
  }

  #pragma unroll
  for (int nf = 0; nf < 4; ++nf)
    #pragma unroll
    for (int r = 0; r < 4; ++r)
      Epi[w * 16 + hi * 4 + r][nf * 16 + m] = acc[nf][r];
  __syncthreads();

  if (g.epmode == 1) {
    const float* res = (isB ? g.resB : g.resA) + (size_t)b * O * N_;
    const float* bias = isB ? g.biasB : g.biasA;
    short* Ut = (isB ? g.UtB : g.UtA) + (size_t)b * N_ * O;
    #pragma unroll
    for (int e = 0; e < 2; ++e) {
      int nn = tid & 63;
      int gl = (tid >> 6) + e * 4;
      int ob = ot0 + gl * 8;
      short8 v;
      #pragma unroll
      for (int j = 0; j < 8; ++j)
        v[j] = f2bf(Epi[gl*8 + j][nn] + res[(size_t)(ob + j) * N_ + n0 + nn] + bias[ob + j]);
      int gout = (ot0 >> 3) + gl;
      int pos = (gout & ~7) | ((gout ^ (nn & 7)) & 7);
      *(short8*)(Ut + (size_t)(n0 + nn) * O + pos * 8) = v;
    }
  } else {
    const float* bias = isB ? g.biasB : g.biasA;
    float* outF = isB ? g.outB : g.outA;
    int o = tid >> 2, nq = tid & 3;
    float bv = bias[ot0 + o];
    float* dst = outF + (size_t)b * O * N_ + (size_t)(ot0 + o) * N_ + n0 + nq * 16;
    #pragma unroll
    for (int q4 = 0; q4 < 4; ++q4) {
      float4 vv = { Epi[o][nq*16 + q4*4 + 0] + bv, Epi[o][nq*16 + q4*4 + 1] + bv,
                    Epi[o][nq*16 + q4*4 + 2] + bv, Epi[o][nq*16 + q4*4 + 3] + bv };
      *(float4*)(dst + q4 * 4) = vv;
    }
  }
}

// ---------------------------------------------------------------------------
extern "C" void kernel_launch(void* const* d_in, const int* in_sizes, int n_in,
                              void* d_out, int out_size, void* d_ws, size_t ws_size,
                              hipStream_t stream) {
  (void)in_sizes; (void)n_in; (void)out_size; (void)ws_size;
  const float* ll  = (const float*)d_in[0];
  const float* hf  = (const float*)d_in[1];
  const float* Wqh = (const float*)d_in[2];
  const float* Wkh = (const float*)d_in[3];
  const float* Wvh = (const float*)d_in[4];
  const float* Wql = (const float*)d_in[5];
  const float* Wkl = (const float*)d_in[6];
  const float* Wvl = (const float*)d_in[7];
  const float* Wph = (const float*)d_in[8];
  const float* bph = (const float*)d_in[9];
  const float* Wpl = (const float*)d_in[10];
  const float* bpl = (const float*)d_in[11];
  const float* Wah = (const float*)d_in[12];
  const float* bah = (const float*)d_in[13];
  const float* Wal = (const float*)d_in[14];
  const float* bal = (const float*)d_in[15];
  const float* alpha = (const float*)d_in[16];

  float* ws = (float*)d_ws;
  const size_t BDN = (size_t)B_ * D_ * N_;
  float* Mrl = ws;
  float* Mrh = Mrl + BDN;
  float* Mcl = Mrh + BDN;
  float* Mch = Mcl + BDN;
  float* Mdl = Mch + BDN;
  float* Mdh = Mdl + (size_t)B_ * D_ * 128;
  short* sp = (short*)(Mdh + (size_t)B_ * D_ * 128);
  short* Qhb = sp;           sp += BDN;
  short* Qlb = sp;           sp += BDN;
  short* Khb = sp;           sp += BDN;
  short* Klb = sp;           sp += BDN;
  short* Vhb = sp;           sp += BDN;
  short* Vlb = sp;           sp += BDN;
  short* Qht = sp;           sp += BDN;
  short* Qlt = sp;           sp += BDN;
  short* Kht = sp;           sp += BDN;
  short* Klt = sp;           sp += BDN;
  short* Vht = sp;           sp += BDN;
  short* Vlt = sp;           sp += BDN;
  short* Mtbl = Qht;                            // dead after attn_sm
  short* Mtbh = Qlt;
  short* Utl  = Kht;
  short* Uth  = Klt;

  dim3 blk(256, 1, 1);
  const float qscale = (float)(0.08838834764831845 * 1.4426950408889634);
  float* out = (float*)d_out;

  // 1) fused QKV MFMA GEMMs with inline X transpose (xt fused away)
  QkvP qp{Wqh, Wkh, Wvh, Wql, Wkl, Wvl, hf, ll,
          Qhb, Khb, Vhb, Qht, Kht, Qlb, Klb, Vlb, Qlt, Klt, qscale};
  qkv_kernel<<<dim3(N_/64, 6, 2*B_), blk, 0, stream>>>(qp);

  // 2) image-transposed V copies for cols attention
  vt_kernel<<<dim3(64, 2), blk, 0, stream>>>(Vhb, Vlb, Vht, Vlt);

  // 3) fused rows+cols+diag attention (independent stores to Mr/Mc/Md)
  SmP smp{Qhb, Qlb, Khb, Klb, Vhb, Vlb, Qht, Qlt, Kht, Klt, Vht, Vlt,
          Mrl, Mrh, Mcl, Mch, Mdl, Mdh, alpha};
  attn_sm<<<dim3(520, 1, 1), blk, 0, stream>>>(smp);

  // 4) global attention (sums Mr+Mc+Md, emits M^T bf16) — round-11 version
  GlobalAttnParams gp{Qhb, Qlb, Khb, Klb, Vhb, Vlb,
                      Mrl, Mrh, Mcl, Mch, Mdl, Mdh, Mtbl, Mtbh, alpha};
  attn_gl_kernel<<<dim3(256, 1, 1), dim3(512,1,1), 0, stream>>>(gp);

  // 5) U = x + Wp @ M + bp  (both streams, one launch; emit U^T bf16)
  Gemm2P wp{Wpl, Mtbl, ll, bpl, nullptr, Utl, D_, CL_,
            Wph, Mtbh, hf, bph, nullptr, Uth, D_, CH_, 1, 1};
  gemm2_bf16<<<dim3(N_/64, 4, B_), blk, 0, stream>>>(wp);

  // 6) out = Wa @ U + ba  (both streams, one launch)
  Gemm2P wa{Wal, Utl, nullptr, bal, out, nullptr, CL_, CL_,
            Wah, Uth, nullptr, bah, out + (size_t)B_*CL_*N_, nullptr, CH_, CH_, 1, 2};
  gemm2_bf16<<<dim3(N_/64, 4, B_), blk, 0, stream>>>(wa);
}